// Round 11
// baseline (469.421 us; speedup 1.0000x reference)
//
#include <hip/hip_runtime.h>
#include <hip/hip_bf16.h>
#include <type_traits>

#define NN 50000
#define NP 8                    // node partitions (one per XCD)
#define PN ((NN + NP - 1) / NP) // 6250 nodes per partition (25KB LDS histogram)
#define KE2 64                  // edges per thread in hist/scat => chunk = 16384

typedef __attribute__((ext_vector_type(8))) short bf16x8;
typedef __attribute__((ext_vector_type(4))) float f32x4;
typedef unsigned int u32;

__device__ __forceinline__ ushort f2bf(float f) {
    unsigned u = __builtin_bit_cast(unsigned, f);
    unsigned r = (u + 0x7fffu + ((u >> 16) & 1u)) >> 16;  // RTN-even
    return (ushort)r;
}
__device__ __forceinline__ float bflo(unsigned v) { return __builtin_bit_cast(float, v << 16); }
__device__ __forceinline__ float bfhi(unsigned v) { return __builtin_bit_cast(float, v & 0xffff0000u); }

// async global->LDS, 16B per lane; LDS dest = wave-uniform base + lane*16.
__device__ __forceinline__ void gld16(const void* g, void* l) {
    __builtin_amdgcn_global_load_lds((const __attribute__((address_space(1))) u32*)g,
                                     (__attribute__((address_space(3))) u32*)l, 16, 0, 0);
}

// ---------------------------------------------------------------------------
// Fused: edge dtype detect + all three weight transpose+casts.
__global__ void k_initw(const unsigned int* ei, int npairs, int* flag,
                        const float* __restrict__ W0, ushort* __restrict__ WT0,
                        const float* __restrict__ W1, ushort* __restrict__ WT1,
                        const float* __restrict__ W2, ushort* __restrict__ WT2) {
    int id = blockIdx.x * 256 + threadIdx.x;
    if (blockIdx.x == 0) {
        __shared__ int any_nz;
        if (threadIdx.x == 0) any_nz = 0;
        __syncthreads();
        for (int p = threadIdx.x; p < npairs; p += blockDim.x) {
            if (ei[2 * p + 1] != 0u) atomicOr(&any_nz, 1);
        }
        __syncthreads();
        if (threadIdx.x == 0) *flag = (any_nz == 0) ? 1 : 0;
    }
    const float* W; ushort* WT; int K, N, loc;
    if (id < 131072)      { W = W0; WT = WT0; K = 512; N = 256; loc = id; }
    else if (id < 196608) { W = W1; WT = WT1; K = 256; N = 256; loc = id - 131072; }
    else if (id < 229376) { W = W2; WT = WT2; K = 256; N = 128; loc = id - 196608; }
    else return;
    int nn = loc / K, k = loc - nn * K;
    WT[loc] = f2bf(W[(long long)k * N + nn]);
}

__device__ __forceinline__ int load_idx(const void* ei, long long pos, int is64) {
    return is64 ? (int)(((const long long*)ei)[pos]) : ((const int*)ei)[pos];
}

// ---------------------------------------------------------------------------
// Atomic-free counting sort (R10 PMC: 1.6M device-scope atomic RMWs cap at
// ~24 G RMW/s = 66us regardless of padding; the RMW COUNT had to go).
// Pass 1: block (p,c) = (partition, edge-chunk) builds a PN-bin LDS histogram
// of chunk c's dsts in partition p's range, then stores it (plain stores).
__global__ __launch_bounds__(256) void k_hist(const void* ei, long long E,
                                              const int* __restrict__ flag,
                                              int* __restrict__ hist, int n, int C) {
    __shared__ int lh[PN];
    int p = blockIdx.x & (NP - 1), c = blockIdx.x >> 3;
    int lo = p * PN;
    int hi = lo + PN; if (hi > n) hi = n;
    int len = hi - lo;
    for (int i = threadIdx.x; i < len; i += 256) lh[i] = 0;
    __syncthreads();
    int is64 = *flag;
    long long cbase = (long long)c * (256 * KE2);
    for (int k = 0; k < KE2; ++k) {
        long long e = cbase + k * 256 + threadIdx.x;
        if (e < E) {
            int dst = load_idx(ei, E + e, is64);
            if (dst >= lo && dst < hi) atomicAdd(&lh[dst - lo], 1);
        }
    }
    __syncthreads();
    int* gh = hist + ((long long)p * C + c) * PN;
    for (int i = threadIdx.x; i < len; i += 256) gh[i] = lh[i];
}

// Per-node prefix over chunk histograms (in-place -> chunk bases), producing
// total degree cnt[i] and dinv. Coalesced 200KB column sweeps.
__global__ void k_cscan(int* __restrict__ hist, int* __restrict__ cnt,
                        float* __restrict__ dinv, int n, int C) {
    int i = blockIdx.x * 256 + threadIdx.x;
    if (i >= n) return;
    int p = i / PN, li = i - p * PN;
    int* col = hist + ((long long)p * C) * PN + li;
    int acc = 0;
    for (int c = 0; c < C; ++c) {
        int t = col[(long long)c * PN];
        col[(long long)c * PN] = acc;
        acc += t;
    }
    cnt[i] = acc;
    dinv[i] = rsqrtf((float)(acc + 1));  // +1: self loop
}

// ---------------------------------------------------------------------------
// Two-level grid scan of padded counts (R9 lesson: no single-block scans).
__global__ __launch_bounds__(1024) void k_scan_a(const int* __restrict__ cnt,
                                                 int* __restrict__ bsum, int n) {
    __shared__ int wsum[16];
    int i = blockIdx.x * 1024 + threadIdx.x;
    int lane = (int)threadIdx.x & 63, w = (int)threadIdx.x >> 6;
    int v = (i < n) ? cnt[i] : 0;
    int pv = (v + 7) & ~7;
    int s = pv;
#pragma unroll
    for (int off = 1; off < 64; off <<= 1) s += __shfl_xor(s, off);
    if (lane == 0) wsum[w] = s;
    __syncthreads();
    if (threadIdx.x == 0) {
        int t = 0;
#pragma unroll
        for (int k = 0; k < 16; ++k) t += wsum[k];
        bsum[blockIdx.x] = t;
    }
}

__global__ void k_scan_b(const int* __restrict__ bsum, int* __restrict__ bbase,
                         int* __restrict__ offs_n, int nb) {
    int lane = (int)threadIdx.x;  // 64 threads, nb <= 64
    int v = (lane < nb) ? bsum[lane] : 0;
    int x = v;
#pragma unroll
    for (int off = 1; off < 64; off <<= 1) {
        int y = __shfl_up(x, off);
        if (lane >= off) x += y;
    }
    if (lane < nb) bbase[lane] = x - v;
    if (lane == nb - 1) *offs_n = x;
}

__global__ __launch_bounds__(1024) void k_scan_c(const int* __restrict__ cnt,
                                                 const int* __restrict__ bbase,
                                                 int* __restrict__ offs, int n) {
    __shared__ int wsum[16];
    int i = blockIdx.x * 1024 + threadIdx.x;
    int lane = (int)threadIdx.x & 63, w = (int)threadIdx.x >> 6;
    int v = (i < n) ? cnt[i] : 0;
    int pv = (v + 7) & ~7;
    int x = pv;
#pragma unroll
    for (int off = 1; off < 64; off <<= 1) {
        int y = __shfl_up(x, off);
        if (lane >= off) x += y;
    }
    if (lane == 63) wsum[w] = x;
    __syncthreads();
    if (w == 0) {
        int pvv = (lane < 16) ? wsum[lane] : 0;
#pragma unroll
        for (int off = 1; off < 16; off <<= 1) {
            int py = __shfl_up(pvv, off);
            if (lane >= off) pvv += py;
        }
        if (lane < 16) wsum[lane] = pvv;
    }
    __syncthreads();
    int wbase = (w > 0) ? wsum[w - 1] : 0;
    if (i < n) offs[i] = bbase[blockIdx.x] + wbase + x - pv;
}

// Pass 2: re-scan chunks; LDS cur gives the local ordinal, chunk base comes
// from the in-place prefix. pos = offs[dst] + cb[dst] + local. epk writes stay
// partition-local per XCD (R6 write-amplification fix preserved). Extra blocks
// (c >= C) zero-fill the x8 pad slots.
__global__ __launch_bounds__(256) void k_scat(const void* ei, long long E,
                        const int* __restrict__ flag,
                        const float* __restrict__ dinv, const int* __restrict__ offs,
                        const int* __restrict__ hist, int2* __restrict__ epk,
                        const int* __restrict__ cnt, int n, int C) {
    int p = blockIdx.x & (NP - 1), c = blockIdx.x >> 3;
    int lo = p * PN;
    int hi = lo + PN; if (hi > n) hi = n;
    if (c < C) {
        __shared__ int cur[PN];
        int len = hi - lo;
        for (int i = threadIdx.x; i < len; i += 256) cur[i] = 0;
        __syncthreads();
        int is64 = *flag;
        const int* cb = hist + ((long long)p * C + c) * PN;
        long long cbase = (long long)c * (256 * KE2);
        for (int k = 0; k < KE2; ++k) {
            long long e = cbase + k * 256 + threadIdx.x;
            if (e < E) {
                int dst = load_idx(ei, E + e, is64);
                if (dst >= lo && dst < hi) {
                    int loc = atomicAdd(&cur[dst - lo], 1);  // LDS atomic (on-CU)
                    int src = load_idx(ei, e, is64);
                    int pos = offs[dst] + cb[dst - lo] + loc;
                    epk[pos] = make_int2(src, __builtin_bit_cast(int, dinv[src] * dinv[dst]));
                }
            }
        }
    } else {
        int i = lo + (c - C) * 256 + (int)threadIdx.x;
        if (i < hi) {
            int b = offs[i] + cnt[i], en = offs[i + 1];
            for (int j = b; j < en; ++j) epk[j] = make_int2(0, 0);
        }
    }
}

// x (f32) -> bf16, vectorized: each thread converts 8 floats -> 16B store.
__global__ void k_x2bf(const float* __restrict__ x, ushort* __restrict__ xbf, long long n8) {
    long long id = (long long)blockIdx.x * blockDim.x + threadIdx.x;
    if (id < n8) {
        const float* src = x + id * 8;
        float4 f0 = *(const float4*)src;
        float4 f1 = *(const float4*)(src + 4);
        ushort tmp[8] = {f2bf(f0.x), f2bf(f0.y), f2bf(f0.z), f2bf(f0.w),
                         f2bf(f1.x), f2bf(f1.y), f2bf(f1.z), f2bf(f1.w)};
        *(uint4*)&xbf[id * 8] = *(uint4*)tmp;
    }
}

// ---------------------------------------------------------------------------
// bf16 MFMA GEMM: C[M,N] = A[M,K] * WT[N,K]^T, 128x128 tile, BK=64, 4 waves.
// LDS layout per tile: [128 rows][8 slots of 8 bf16], slot XOR-swizzled by row&7.
// Staging via global_load_lds(16B): linear LDS dest, source slot pre-swizzled
// (m173 pattern) so the MFMA-side LOFF reads are unchanged.
#define LOFF(r, s) (((r) * 8 + ((s) ^ ((r) & 7))) * 8)

template <typename TA>
__global__ __launch_bounds__(256) void k_gemm_mfma(const TA* __restrict__ A,
                                                   const ushort* __restrict__ WT,
                                                   ushort* __restrict__ C,
                                                   int M, int N, int K) {
    __shared__ ushort As[8192];
    __shared__ ushort Bs[8192];
    int t = threadIdx.x;
    int lane = t & 63;
    int w = t >> 6;
    int wr = (w >> 1) * 64, wc = (w & 1) * 64;
    int m0 = blockIdx.y * 128, n0 = blockIdx.x * 128;

    f32x4 acc[4][4] = {};

    for (int k0 = 0; k0 < K; k0 += 64) {
        // ---- B tile: 16 x 1KB regions; wave w stages regions w*4+j ----
#pragma unroll
        for (int j = 0; j < 4; ++j) {
            int id = (w * 4 + j) * 64 + lane;  // linear 16B-slot index
            int r = id >> 3, sp = id & 7;
            int s = sp ^ (r & 7);              // pre-swizzled source slot
            gld16(WT + (long long)(n0 + r) * K + k0 + s * 8, &Bs[(r * 8 + sp) * 8]);
        }
        // ---- A tile ----
        if constexpr (std::is_same<TA, float>::value) {
#pragma unroll
            for (int j = 0; j < 4; ++j) {
                int id = t + j * 256;
                int r = id >> 3, s = id & 7;
                int grow = m0 + r;
                if (grow < M) {
                    const float* src = A + (long long)grow * K + k0 + s * 8;
                    float4 f0 = *(const float4*)src;
                    float4 f1 = *(const float4*)(src + 4);
                    ushort tmp[8] = {f2bf(f0.x), f2bf(f0.y), f2bf(f0.z), f2bf(f0.w),
                                     f2bf(f1.x), f2bf(f1.y), f2bf(f1.z), f2bf(f1.w)};
                    *(uint4*)&As[LOFF(r, s)] = *(uint4*)tmp;
                }
            }
        } else {
#pragma unroll
            for (int j = 0; j < 4; ++j) {
                int rbase = (w * 4 + j) * 8;
                if (m0 + rbase < M) {  // uniform: 8-row regions, M%8==0
                    int id = rbase * 8 + lane;
                    int r = id >> 3, sp = id & 7;
                    int s = sp ^ (r & 7);
                    gld16((const ushort*)A + (long long)(m0 + r) * K + k0 + s * 8,
                          &As[(r * 8 + sp) * 8]);
                }
            }
        }
        __syncthreads();
        // ---- MFMA: each wave computes a 64x64 sub-tile (4x4 fragments) ----
#pragma unroll
        for (int kk = 0; kk < 2; ++kk) {
            int ks = kk * 4 + (lane >> 4);
            bf16x8 a[4], b[4];
#pragma unroll
            for (int m = 0; m < 4; ++m)
                a[m] = *(bf16x8*)&As[LOFF(wr + m * 16 + (lane & 15), ks)];
#pragma unroll
            for (int nn = 0; nn < 4; ++nn)
                b[nn] = *(bf16x8*)&Bs[LOFF(wc + nn * 16 + (lane & 15), ks)];
#pragma unroll
            for (int m = 0; m < 4; ++m)
#pragma unroll
                for (int nn = 0; nn < 4; ++nn)
                    acc[m][nn] = __builtin_amdgcn_mfma_f32_16x16x32_bf16(a[m], b[nn], acc[m][nn], 0, 0, 0);
        }
        __syncthreads();
    }
    // ---- epilogue: D frag (reg i): row=(lane>>4)*4+i, col=lane&15 (m89 layout) ----
#pragma unroll
    for (int m = 0; m < 4; ++m) {
#pragma unroll
        for (int i = 0; i < 4; ++i) {
            int row = m0 + wr + m * 16 + (lane >> 4) * 4 + i;
            if (row < M) {
#pragma unroll
                for (int nn = 0; nn < 4; ++nn) {
                    int col = n0 + wc + nn * 16 + (lane & 15);
                    C[(long long)row * N + col] = f2bf(acc[m][nn][i]);
                }
            }
        }
    }
}

// ---------------------------------------------------------------------------
// Aggregation SLICE: 128 features at offset foff of rows with stride DT.
// out[i, foff:foff+128] = bias + dinv[i]^2*h[i,:] + sum enorm*h[src,:]
// One WAVE per node (lane covers 2 features, u32 packed-bf16 gathers).
template <int DT, bool RELU, bool OUTF32>
__global__ __launch_bounds__(128) void k_aggs(const ushort* __restrict__ h,
                                              const int* __restrict__ offs,
                                              const int2* __restrict__ epk,
                                              const float* __restrict__ dinv,
                                              const float* __restrict__ bias,
                                              void* __restrict__ outp, int n, int foff) {
    int node = __builtin_amdgcn_readfirstlane((int)(blockIdx.x * 2 + (threadIdx.x >> 6)));
    if (node >= n) return;
    int t = (int)threadIdx.x & 63;
    float di = dinv[node];
    float dii = di * di;

    unsigned v0 = *(const unsigned*)&h[(long long)node * DT + foff + t * 2];
    float2 bs = *(const float2*)&bias[foff + t * 2];
    float a0 = bs.x + dii * bflo(v0);
    float a1 = bs.y + dii * bfhi(v0);

    int s = offs[node], e = offs[node + 1];  // uniform -> scalar loads

    for (int j = s; j < e; j += 8) {
        int2 p[8];
#pragma unroll
        for (int u = 0; u < 8; ++u) p[u] = epk[j + u];
        unsigned v[8];
#pragma unroll
        for (int u = 0; u < 8; ++u)
            v[u] = *(const unsigned*)&h[(long long)p[u].x * DT + foff + t * 2];
#pragma unroll
        for (int u = 0; u < 8; ++u) {
            float wgt = __builtin_bit_cast(float, p[u].y);
            a0 += wgt * bflo(v[u]);
            a1 += wgt * bfhi(v[u]);
        }
    }

    if (RELU) { a0 = fmaxf(a0, 0.f); a1 = fmaxf(a1, 0.f); }
    long long oidx = ((long long)node * DT + foff) / 2 + t;
    if constexpr (OUTF32) {
        ((float2*)outp)[oidx] = make_float2(a0, a1);
    } else {
        unsigned pk = (unsigned)f2bf(a0) | ((unsigned)f2bf(a1) << 16);
        ((unsigned*)outp)[oidx] = pk;
    }
}

// ---------------------------------------------------------------------------
extern "C" void kernel_launch(void* const* d_in, const int* in_sizes, int n_in,
                              void* d_out, int out_size, void* d_ws, size_t ws_size,
                              hipStream_t stream) {
    const float* x  = (const float*)d_in[0];
    const void*  ei = d_in[1];
    const float* W0 = (const float*)d_in[2];
    const float* b0 = (const float*)d_in[3];
    const float* W1 = (const float*)d_in[4];
    const float* b1 = (const float*)d_in[5];
    const float* W2 = (const float*)d_in[6];
    const float* b2 = (const float*)d_in[7];
    float* out = (float*)d_out;

    const int n = NN;
    const long long E = (long long)in_sizes[1] / 2;
    const int nbscan = (n + 1023) / 1024;  // 49 <= 64
    const int C = (int)((E + 256 * KE2 - 1) / (256 * KE2));  // edge chunks (98 @ 1.6M)

    char* ws = (char*)d_ws;
    int*    cnt  = (int*)(ws);                                // 200KB
    int*    offs = (int*)(ws + 3400 * 1024);                  // 200KB
    float*  dinv = (float*)(ws + 3700 * 1024);                // 200KB
    int*    flag = (int*)(ws + 3960 * 1024);
    int*    bsum = (int*)(ws + 3964 * 1024);                  // 64 ints
    int*    bbase= (int*)(ws + 3968 * 1024);                  // 64 ints
    int2*   epk  = (int2*)(ws + 4ll * 1024 * 1024);           // (E + 7n)*8B <= 15.7MB
    ushort* WT0  = (ushort*)(ws + 20ll * 1024 * 1024);        // 256KB
    ushort* WT1  = (ushort*)(ws + 20ll * 1024 * 1024 + 512 * 1024);
    ushort* WT2  = (ushort*)(ws + 20ll * 1024 * 1024 + 768 * 1024);
    ushort* hA   = (ushort*)(ws + 21ll * 1024 * 1024);        // 25.6MB
    ushort* hB   = (ushort*)(ws + 47ll * 1024 * 1024);        // 25.6MB
    ushort* xbf  = (ushort*)(ws + 73ll * 1024 * 1024);        // 51.2MB (optional)
    int*    hist = (int*)hB;  // NP*C*PN*4B = 19.6MB; hB not live until agg L0
    const size_t need_xbf = 73ll * 1024 * 1024 + 51200000ll;
    const bool have_xbf = (ws_size >= need_xbf);

    // --- fused init: dtype detect + weight transposes ---
    k_initw<<<(229376 + 255) / 256, 256, 0, stream>>>((const unsigned int*)ei, 4096, flag,
                                                      W0, WT0, W1, WT1, W2, WT2);

    // --- atomic-free counting sort: hist -> cscan -> offs scan -> scatter ---
    k_hist<<<NP * C, 256, 0, stream>>>(ei, E, flag, hist, n, C);
    k_cscan<<<(n + 255) / 256, 256, 0, stream>>>(hist, cnt, dinv, n, C);
    k_scan_a<<<nbscan, 1024, 0, stream>>>(cnt, bsum, n);
    k_scan_b<<<1, 64, 0, stream>>>(bsum, bbase, &offs[n], nbscan);
    k_scan_c<<<nbscan, 1024, 0, stream>>>(cnt, bbase, offs, n);
    {
        int npad = (PN + 255) / 256;  // pad-fill chunks per partition
        k_scat<<<NP * (C + npad), 256, 0, stream>>>(ei, E, flag, dinv, offs, hist, epk, cnt, n, C);
    }
    if (have_xbf) {
        long long n8 = (long long)n * 512 / 8;
        k_x2bf<<<(int)((n8 + 255) / 256), 256, 0, stream>>>(x, xbf, n8);
    }

    int mt = (n + 127) / 128;
    int nb2 = (n + 1) / 2;

    // --- layer 0: x[50000,512] @ W0 -> bf16 h -> relu agg (2 feature slices) ---
    if (have_xbf) {
        k_gemm_mfma<ushort><<<dim3(2, mt), 256, 0, stream>>>(xbf, WT0, hA, n, 256, 512);
    } else {
        k_gemm_mfma<float><<<dim3(2, mt), 256, 0, stream>>>(x, WT0, hA, n, 256, 512);
    }
    k_aggs<256, true, false><<<nb2, 128, 0, stream>>>(hA, offs, epk, dinv, b0, hB, n, 0);
    k_aggs<256, true, false><<<nb2, 128, 0, stream>>>(hA, offs, epk, dinv, b0, hB, n, 128);

    // --- layer 1 ---
    k_gemm_mfma<ushort><<<dim3(2, mt), 256, 0, stream>>>(hB, WT1, hA, n, 256, 256);
    k_aggs<256, true, false><<<nb2, 128, 0, stream>>>(hA, offs, epk, dinv, b1, hB, n, 0);
    k_aggs<256, true, false><<<nb2, 128, 0, stream>>>(hA, offs, epk, dinv, b1, hB, n, 128);

    // --- layer 2 (f32 output) ---
    k_gemm_mfma<ushort><<<dim3(1, mt), 256, 0, stream>>>(hB, WT2, hA, n, 128, 256);
    k_aggs<128, false, true><<<nb2, 128, 0, stream>>>(hA, offs, epk, dinv, b2, out, n, 0);
}

// Round 12
// 437.924 us; speedup vs baseline: 1.0719x; 1.0719x over previous
//
#include <hip/hip_runtime.h>
#include <hip/hip_bf16.h>
#include <type_traits>

#define NN 50000
#define CNT_S 16  // cnt stride (ints): one counter per 64B line (R8->R10: 77->66us)

typedef __attribute__((ext_vector_type(8))) short bf16x8;
typedef __attribute__((ext_vector_type(4))) float f32x4;
typedef unsigned int u32;

__device__ __forceinline__ ushort f2bf(float f) {
    unsigned u = __builtin_bit_cast(unsigned, f);
    unsigned r = (u + 0x7fffu + ((u >> 16) & 1u)) >> 16;  // RTN-even
    return (ushort)r;
}
__device__ __forceinline__ float bflo(unsigned v) { return __builtin_bit_cast(float, v << 16); }
__device__ __forceinline__ float bfhi(unsigned v) { return __builtin_bit_cast(float, v & 0xffff0000u); }

// async global->LDS, 16B per lane; LDS dest = wave-uniform base + lane*16.
__device__ __forceinline__ void gld16(const void* g, void* l) {
    __builtin_amdgcn_global_load_lds((const __attribute__((address_space(1))) u32*)g,
                                     (__attribute__((address_space(3))) u32*)l, 16, 0, 0);
}

__device__ __forceinline__ int load_idx(const void* ei, long long pos, int is64) {
    return is64 ? (int)(((const long long*)ei)[pos]) : ((const int*)ei)[pos];
}

// ---------------------------------------------------------------------------
// Fused init: padded-cnt zero + dtype detect + weight transposes, with the
// x f32->bf16 convert as tail blocks (concurrent, not serialized).
__global__ void k_initw(int* cnt, int ncnt, const unsigned int* ei, int npairs, int* flag,
                        const float* __restrict__ W0, ushort* __restrict__ WT0,
                        const float* __restrict__ W1, ushort* __restrict__ WT1,
                        const float* __restrict__ W2, ushort* __restrict__ WT2,
                        const float* __restrict__ x, ushort* __restrict__ xbf,
                        long long n8, int nbi) {
    if ((int)blockIdx.x >= nbi) {  // ---- x2bf tail blocks ----
        long long id = (long long)(blockIdx.x - nbi) * 256 + threadIdx.x;
        if (id < n8) {
            const float* src = x + id * 8;
            float4 f0 = *(const float4*)src;
            float4 f1 = *(const float4*)(src + 4);
            ushort tmp[8] = {f2bf(f0.x), f2bf(f0.y), f2bf(f0.z), f2bf(f0.w),
                             f2bf(f1.x), f2bf(f1.y), f2bf(f1.z), f2bf(f1.w)};
            *(uint4*)&xbf[id * 8] = *(uint4*)tmp;
        }
        return;
    }
    int id = blockIdx.x * 256 + threadIdx.x;
    if (id < ncnt) cnt[id] = 0;
    if (blockIdx.x == 0) {
        __shared__ int any_nz;
        if (threadIdx.x == 0) any_nz = 0;
        __syncthreads();
        for (int p = threadIdx.x; p < npairs; p += blockDim.x) {
            if (ei[2 * p + 1] != 0u) atomicOr(&any_nz, 1);
        }
        __syncthreads();
        if (threadIdx.x == 0) *flag = (any_nz == 0) ? 1 : 0;
    }
    const float* W; ushort* WT; int K, N, loc;
    if (id < 131072)      { W = W0; WT = WT0; K = 512; N = 256; loc = id; }
    else if (id < 196608) { W = W1; WT = WT1; K = 256; N = 256; loc = id - 131072; }
    else if (id < 229376) { W = W2; WT = WT2; K = 256; N = 128; loc = id - 196608; }
    else return;
    int nn = loc / K, k = loc - nn * K;
    WT[loc] = f2bf(W[(long long)k * N + nn]);
}

// ---------------------------------------------------------------------------
// LDS layout per GEMM tile: [128 rows][8 slots of 8 bf16], XOR-swizzled.
#define LOFF(r, s) (((r) * 8 + ((s) ^ ((r) & 7))) * 8)

// GEMM tile body (bf16 A), shared by the fused kernel and the standalone one.
__device__ __forceinline__ void gemm_tile_u16(const ushort* __restrict__ A,
                                              const ushort* __restrict__ WT,
                                              ushort* __restrict__ C,
                                              int M, int N, int K, int m0, int n0,
                                              ushort* As, ushort* Bs) {
    int t = threadIdx.x;
    int lane = t & 63;
    int w = t >> 6;
    int wr = (w >> 1) * 64, wc = (w & 1) * 64;
    f32x4 acc[4][4] = {};
    for (int k0 = 0; k0 < K; k0 += 64) {
#pragma unroll
        for (int j = 0; j < 4; ++j) {
            int id = (w * 4 + j) * 64 + lane;
            int r = id >> 3, sp = id & 7;
            int s = sp ^ (r & 7);
            gld16(WT + (long long)(n0 + r) * K + k0 + s * 8, &Bs[(r * 8 + sp) * 8]);
        }
#pragma unroll
        for (int j = 0; j < 4; ++j) {
            int rbase = (w * 4 + j) * 8;
            if (m0 + rbase < M) {  // uniform: 8-row regions, M%8==0
                int id = rbase * 8 + lane;
                int r = id >> 3, sp = id & 7;
                int s = sp ^ (r & 7);
                gld16(A + (long long)(m0 + r) * K + k0 + s * 8, &As[(r * 8 + sp) * 8]);
            }
        }
        __syncthreads();
#pragma unroll
        for (int kk = 0; kk < 2; ++kk) {
            int ks = kk * 4 + (lane >> 4);
            bf16x8 a[4], b[4];
#pragma unroll
            for (int m = 0; m < 4; ++m)
                a[m] = *(bf16x8*)&As[LOFF(wr + m * 16 + (lane & 15), ks)];
#pragma unroll
            for (int nn = 0; nn < 4; ++nn)
                b[nn] = *(bf16x8*)&Bs[LOFF(wc + nn * 16 + (lane & 15), ks)];
#pragma unroll
            for (int m = 0; m < 4; ++m)
#pragma unroll
                for (int nn = 0; nn < 4; ++nn)
                    acc[m][nn] = __builtin_amdgcn_mfma_f32_16x16x32_bf16(a[m], b[nn], acc[m][nn], 0, 0, 0);
        }
        __syncthreads();
    }
#pragma unroll
    for (int m = 0; m < 4; ++m) {
#pragma unroll
        for (int i = 0; i < 4; ++i) {
            int row = m0 + wr + m * 16 + (lane >> 4) * 4 + i;
            if (row < M) {
#pragma unroll
                for (int nn = 0; nn < 4; ++nn) {
                    int col = n0 + wc + nn * 16 + (lane & 15);
                    C[(long long)row * N + col] = f2bf(acc[m][nn][i]);
                }
            }
        }
    }
}

// Fused: degree-count atomics (latency-bound, <1% VALU) + GEMM L0 tiles
// (MFMA-bound, graph-independent) in one dispatch. R8 showed streaming work
// contends with the atomic path; MFMA work uses a different pipe.
__global__ __launch_bounds__(256) void k_countg(const void* ei, long long E,
                                                const int* __restrict__ flag,
                                                int* cnt, int* __restrict__ ord, int nbc,
                                                const ushort* __restrict__ A,
                                                const ushort* __restrict__ WT,
                                                ushort* __restrict__ C, int M, int N, int K) {
    __shared__ ushort As[8192];
    __shared__ ushort Bs[8192];
    if ((int)blockIdx.x < nbc) {
        long long e = (long long)blockIdx.x * 256 + threadIdx.x;
        if (e < E) {
            int dst = load_idx(ei, E + e, *flag);
            ord[e] = atomicAdd(&cnt[(long long)dst * CNT_S], 1);
        }
        return;
    }
    int b = (int)blockIdx.x - nbc;       // 782 GEMM tiles: (m-tile = b>>1, n-tile = b&1)
    gemm_tile_u16(A, WT, C, M, N, K, (b >> 1) * 128, (b & 1) * 128, As, Bs);
}

// standalone count (fallback path without xbf)
__global__ void k_count(const void* ei, long long E, const int* flag,
                        int* cnt, int* __restrict__ ord) {
    long long e = (long long)blockIdx.x * blockDim.x + threadIdx.x;
    if (e < E) {
        int dst = load_idx(ei, E + e, *flag);
        ord[e] = atomicAdd(&cnt[(long long)dst * CNT_S], 1);
    }
}

// ---------------------------------------------------------------------------
// Two-level grid scan of padded counts (R9 lesson: no single-block scans).
__global__ __launch_bounds__(1024) void k_scan_a(const int* __restrict__ cnt,
                                                 int* __restrict__ bsum,
                                                 float* __restrict__ dinv, int n) {
    __shared__ int wsum[16];
    int i = blockIdx.x * 1024 + threadIdx.x;
    int lane = (int)threadIdx.x & 63, w = (int)threadIdx.x >> 6;
    int v = (i < n) ? cnt[(long long)i * CNT_S] : 0;
    int pv = (v + 7) & ~7;
    if (i < n) dinv[i] = rsqrtf((float)(v + 1));  // +1: self loop
    int s = pv;
#pragma unroll
    for (int off = 1; off < 64; off <<= 1) s += __shfl_xor(s, off);
    if (lane == 0) wsum[w] = s;
    __syncthreads();
    if (threadIdx.x == 0) {
        int t = 0;
#pragma unroll
        for (int k = 0; k < 16; ++k) t += wsum[k];
        bsum[blockIdx.x] = t;
    }
}

__global__ void k_scan_b(const int* __restrict__ bsum, int* __restrict__ bbase,
                         int* __restrict__ offs_n, int nb) {
    int lane = (int)threadIdx.x;  // 64 threads, nb <= 64
    int v = (lane < nb) ? bsum[lane] : 0;
    int x = v;
#pragma unroll
    for (int off = 1; off < 64; off <<= 1) {
        int y = __shfl_up(x, off);
        if (lane >= off) x += y;
    }
    if (lane < nb) bbase[lane] = x - v;
    if (lane == nb - 1) *offs_n = x;
}

__global__ __launch_bounds__(1024) void k_scan_c(const int* __restrict__ cnt,
                                                 const int* __restrict__ bbase,
                                                 int* __restrict__ offs, int n) {
    __shared__ int wsum[16];
    int i = blockIdx.x * 1024 + threadIdx.x;
    int lane = (int)threadIdx.x & 63, w = (int)threadIdx.x >> 6;
    int v = (i < n) ? cnt[(long long)i * CNT_S] : 0;
    int pv = (v + 7) & ~7;
    int x = pv;
#pragma unroll
    for (int off = 1; off < 64; off <<= 1) {
        int y = __shfl_up(x, off);
        if (lane >= off) x += y;
    }
    if (lane == 63) wsum[w] = x;
    __syncthreads();
    if (w == 0) {
        int pvv = (lane < 16) ? wsum[lane] : 0;
#pragma unroll
        for (int off = 1; off < 16; off <<= 1) {
            int py = __shfl_up(pvv, off);
            if (lane >= off) pvv += py;
        }
        if (lane < 16) wsum[lane] = pvv;
    }
    __syncthreads();
    int wbase = (w > 0) ? wsum[w - 1] : 0;
    if (i < n) offs[i] = bbase[blockIdx.x] + wbase + x - pv;
}

// XCD-partitioned bucket scatter (R6: kills the 8x cross-XCD partial-line
// write amplification). No atomics: pos = offs[dst] + ord[e].
#define KE 8
__global__ void k_bucket(const void* ei, long long E, const int* __restrict__ flag,
                         const float* __restrict__ dinv, const int* __restrict__ offs,
                         const int* __restrict__ ord, int2* __restrict__ epk,
                         const int* __restrict__ cnt, int n, int nchunk_e, int pn) {
    int p = blockIdx.x & 7;
    int c = blockIdx.x >> 3;
    int lo = p * pn;
    int hi = lo + pn; if (hi > n) hi = n;
    if (c < nchunk_e) {
        int is64 = *flag;
        long long base = (long long)c * (256 * KE) + threadIdx.x;
#pragma unroll
        for (int k = 0; k < KE; ++k) {
            long long e = base + k * 256;
            if (e < E) {
                int dst = load_idx(ei, E + e, is64);
                if (dst >= lo && dst < hi) {
                    int src = load_idx(ei, e, is64);
                    int pos = offs[dst] + ord[e];
                    epk[pos] = make_int2(src, __builtin_bit_cast(int, dinv[src] * dinv[dst]));
                }
            }
        }
    } else {
        int i = lo + (c - nchunk_e) * 256 + (int)threadIdx.x;
        if (i < hi) {
            int b = offs[i] + cnt[(long long)i * CNT_S], en = offs[i + 1];
            for (int j = b; j < en; ++j) epk[j] = make_int2(0, 0);
        }
    }
}

// ---------------------------------------------------------------------------
// standalone GEMM (f32-A fallback for layer 0, and layers 1/2)
template <typename TA>
__global__ __launch_bounds__(256) void k_gemm_mfma(const TA* __restrict__ A,
                                                   const ushort* __restrict__ WT,
                                                   ushort* __restrict__ C,
                                                   int M, int N, int K) {
    __shared__ ushort As[8192];
    __shared__ ushort Bs[8192];
    int m0 = blockIdx.y * 128, n0 = blockIdx.x * 128;
    if constexpr (std::is_same<TA, float>::value) {
        int t = threadIdx.x;
        int lane = t & 63;
        int w = t >> 6;
        int wr = (w >> 1) * 64, wc = (w & 1) * 64;
        f32x4 acc[4][4] = {};
        for (int k0 = 0; k0 < K; k0 += 64) {
#pragma unroll
            for (int j = 0; j < 4; ++j) {
                int id = (w * 4 + j) * 64 + lane;
                int r = id >> 3, sp = id & 7;
                int s = sp ^ (r & 7);
                gld16(WT + (long long)(n0 + r) * K + k0 + s * 8, &Bs[(r * 8 + sp) * 8]);
            }
#pragma unroll
            for (int j = 0; j < 4; ++j) {
                int id = t + j * 256;
                int r = id >> 3, s = id & 7;
                int grow = m0 + r;
                if (grow < M) {
                    const float* src = A + (long long)grow * K + k0 + s * 8;
                    float4 f0 = *(const float4*)src;
                    float4 f1 = *(const float4*)(src + 4);
                    ushort tmp[8] = {f2bf(f0.x), f2bf(f0.y), f2bf(f0.z), f2bf(f0.w),
                                     f2bf(f1.x), f2bf(f1.y), f2bf(f1.z), f2bf(f1.w)};
                    *(uint4*)&As[LOFF(r, s)] = *(uint4*)tmp;
                }
            }
            __syncthreads();
#pragma unroll
            for (int kk = 0; kk < 2; ++kk) {
                int ks = kk * 4 + (lane >> 4);
                bf16x8 a[4], b[4];
#pragma unroll
                for (int m = 0; m < 4; ++m)
                    a[m] = *(bf16x8*)&As[LOFF(wr + m * 16 + (lane & 15), ks)];
#pragma unroll
                for (int nn = 0; nn < 4; ++nn)
                    b[nn] = *(bf16x8*)&Bs[LOFF(wc + nn * 16 + (lane & 15), ks)];
#pragma unroll
                for (int m = 0; m < 4; ++m)
#pragma unroll
                    for (int nn = 0; nn < 4; ++nn)
                        acc[m][nn] = __builtin_amdgcn_mfma_f32_16x16x32_bf16(a[m], b[nn], acc[m][nn], 0, 0, 0);
            }
            __syncthreads();
        }
#pragma unroll
        for (int m = 0; m < 4; ++m) {
#pragma unroll
            for (int i = 0; i < 4; ++i) {
                int row = m0 + wr + m * 16 + (lane >> 4) * 4 + i;
                if (row < M) {
#pragma unroll
                    for (int nn = 0; nn < 4; ++nn) {
                        int col = n0 + wc + nn * 16 + (lane & 15);
                        C[(long long)row * N + col] = f2bf(acc[m][nn][i]);
                    }
                }
            }
        }
    } else {
        gemm_tile_u16(A, WT, C, M, N, K, m0, n0, As, Bs);
    }
}

// ---------------------------------------------------------------------------
// Aggregation SLICE: 128 features at offset foff of rows with stride DT.
// One WAVE per node (lane covers 2 features, u32 packed-bf16 gathers).
template <int DT, bool RELU, bool OUTF32>
__global__ __launch_bounds__(128) void k_aggs(const ushort* __restrict__ h,
                                              const int* __restrict__ offs,
                                              const int2* __restrict__ epk,
                                              const float* __restrict__ dinv,
                                              const float* __restrict__ bias,
                                              void* __restrict__ outp, int n, int foff) {
    int node = __builtin_amdgcn_readfirstlane((int)(blockIdx.x * 2 + (threadIdx.x >> 6)));
    if (node >= n) return;
    int t = (int)threadIdx.x & 63;
    float di = dinv[node];
    float dii = di * di;

    unsigned v0 = *(const unsigned*)&h[(long long)node * DT + foff + t * 2];
    float2 bs = *(const float2*)&bias[foff + t * 2];
    float a0 = bs.x + dii * bflo(v0);
    float a1 = bs.y + dii * bfhi(v0);

    int s = offs[node], e = offs[node + 1];  // uniform -> scalar loads

    for (int j = s; j < e; j += 8) {
        int2 p[8];
#pragma unroll
        for (int u = 0; u < 8; ++u) p[u] = epk[j + u];
        unsigned v[8];
#pragma unroll
        for (int u = 0; u < 8; ++u)
            v[u] = *(const unsigned*)&h[(long long)p[u].x * DT + foff + t * 2];
#pragma unroll
        for (int u = 0; u < 8; ++u) {
            float wgt = __builtin_bit_cast(float, p[u].y);
            a0 += wgt * bflo(v[u]);
            a1 += wgt * bfhi(v[u]);
        }
    }

    if (RELU) { a0 = fmaxf(a0, 0.f); a1 = fmaxf(a1, 0.f); }
    long long oidx = ((long long)node * DT + foff) / 2 + t;
    if constexpr (OUTF32) {
        ((float2*)outp)[oidx] = make_float2(a0, a1);
    } else {
        unsigned pk = (unsigned)f2bf(a0) | ((unsigned)f2bf(a1) << 16);
        ((unsigned*)outp)[oidx] = pk;
    }
}

// ---------------------------------------------------------------------------
extern "C" void kernel_launch(void* const* d_in, const int* in_sizes, int n_in,
                              void* d_out, int out_size, void* d_ws, size_t ws_size,
                              hipStream_t stream) {
    const float* x  = (const float*)d_in[0];
    const void*  ei = d_in[1];
    const float* W0 = (const float*)d_in[2];
    const float* b0 = (const float*)d_in[3];
    const float* W1 = (const float*)d_in[4];
    const float* b1 = (const float*)d_in[5];
    const float* W2 = (const float*)d_in[6];
    const float* b2 = (const float*)d_in[7];
    float* out = (float*)d_out;

    const int n = NN;
    const long long E = (long long)in_sizes[1] / 2;
    const int ncnt = n * CNT_S;            // 800k ints = 3.2MB (line-padded counters)
    const int nbscan = (n + 1023) / 1024;  // 49 <= 64

    char* ws = (char*)d_ws;
    int*    cnt  = (int*)(ws);                                // [0, 3.2MB)
    int*    offs = (int*)(ws + 3400 * 1024);                  // 200KB
    float*  dinv = (float*)(ws + 3700 * 1024);                // 200KB
    int*    flag = (int*)(ws + 3960 * 1024);
    int*    bsum = (int*)(ws + 3964 * 1024);                  // 64 ints
    int*    bbase= (int*)(ws + 3968 * 1024);                  // 64 ints
    int2*   epk  = (int2*)(ws + 4ll * 1024 * 1024);           // (E + 7n)*8B <= 15.7MB
    ushort* WT0  = (ushort*)(ws + 20ll * 1024 * 1024);        // 256KB
    ushort* WT1  = (ushort*)(ws + 20ll * 1024 * 1024 + 512 * 1024);
    ushort* WT2  = (ushort*)(ws + 20ll * 1024 * 1024 + 768 * 1024);
    ushort* hA   = (ushort*)(ws + 21ll * 1024 * 1024);        // 25.6MB
    ushort* hB   = (ushort*)(ws + 47ll * 1024 * 1024);        // 25.6MB
    ushort* xbf  = (ushort*)(ws + 73ll * 1024 * 1024);        // 51.2MB (optional)
    int*    ord  = (int*)hB;  // E*4B <= 6.4MB; hB not live until agg L0 output
    const size_t need_xbf = 73ll * 1024 * 1024 + 51200000ll;
    const bool have_xbf = (ws_size >= need_xbf);

    const int nbi = (ncnt + 255) / 256;  // 3125 blocks: cnt zero + wt + flag
    const long long n8 = (long long)n * 512 / 8;
    const int nbx = have_xbf ? (int)((n8 + 255) / 256) : 0;

    // --- fused init: padded-cnt zero + dtype detect + wt + x2bf tail ---
    k_initw<<<nbi + nbx, 256, 0, stream>>>(cnt, ncnt, (const unsigned int*)ei, 4096, flag,
                                           W0, WT0, W1, WT1, W2, WT2, x, xbf, n8, nbi);

    int mt = (n + 127) / 128;
    int nb2 = (n + 1) / 2;
    const int nbc = (int)((E + 255) / 256);

    // --- count atomics + GEMM L0 tiles fused (atomic window is 99% idle;
    //     MFMA work rides in it — R8 showed streaming work contends, MFMA
    //     uses a different pipe) ---
    if (have_xbf) {
        k_countg<<<nbc + 2 * mt, 256, 0, stream>>>(ei, E, flag, cnt, ord, nbc,
                                                   xbf, WT0, hA, n, 256, 512);
    } else {
        k_count<<<nbc, 256, 0, stream>>>(ei, E, flag, cnt, ord);
        k_gemm_mfma<float><<<dim3(2, mt), 256, 0, stream>>>(x, WT0, hA, n, 256, 512);
    }
    k_scan_a<<<nbscan, 1024, 0, stream>>>(cnt, bsum, dinv, n);
    k_scan_b<<<1, 64, 0, stream>>>(bsum, bbase, &offs[n], nbscan);
    k_scan_c<<<nbscan, 1024, 0, stream>>>(cnt, bbase, offs, n);
    {
        int nchunk_e = (int)((E + 256 * KE - 1) / (256 * KE));
        int pn = (n + 7) / 8;
        int nchunk_pad = (pn + 255) / 256;
        k_bucket<<<8 * (nchunk_e + nchunk_pad), 256, 0, stream>>>(
            ei, E, flag, dinv, offs, ord, epk, cnt, n, nchunk_e, pn);
    }

    // --- layer 0 agg (GEMM L0 already done above) ---
    k_aggs<256, true, false><<<nb2, 128, 0, stream>>>(hA, offs, epk, dinv, b0, hB, n, 0);
    k_aggs<256, true, false><<<nb2, 128, 0, stream>>>(hA, offs, epk, dinv, b0, hB, n, 128);

    // --- layer 1 ---
    k_gemm_mfma<ushort><<<dim3(2, mt), 256, 0, stream>>>(hB, WT1, hA, n, 256, 256);
    k_aggs<256, true, false><<<nb2, 128, 0, stream>>>(hA, offs, epk, dinv, b1, hB, n, 0);
    k_aggs<256, true, false><<<nb2, 128, 0, stream>>>(hA, offs, epk, dinv, b1, hB, n, 128);

    // --- layer 2 (f32 output) ---
    k_gemm_mfma<ushort><<<dim3(1, mt), 256, 0, stream>>>(hB, WT2, hA, n, 128, 256);
    k_aggs<128, false, true><<<nb2, 128, 0, stream>>>(hA, offs, epk, dinv, b2, out, n, 0);
}